// Round 23
// baseline (144.027 us; speedup 1.0000x reference)
//
#include <hip/hip_runtime.h>

// Problem constants: B=2, T=2048, C=1024, H=16, S=64
#define BB 2
#define TT 2048
#define CC 1024
#define HH 16
#define SS 64
#define MM (BB * TT)   // 4096

typedef unsigned short u16;
typedef __bf16 bf16x8 __attribute__((ext_vector_type(8)));
typedef float f32x4 __attribute__((ext_vector_type(4)));
typedef float f32x16 __attribute__((ext_vector_type(16)));

#define MFMA16(a, b, c) __builtin_amdgcn_mfma_f32_16x16x32_bf16((a), (b), (c), 0, 0, 0)
#define MFMA32(a, b, c) __builtin_amdgcn_mfma_f32_32x32x16_bf16((a), (b), (c), 0, 0, 0)
// v_cvt_pk_bf16_f32: D[15:0]=bf16(S0), D[31:16]=bf16(S1)
#define CVTPK(d, a, b) asm("v_cvt_pk_bf16_f32 %0, %1, %2" : "=v"(d) : "v"(a), "v"(b))

__device__ inline u16 f2bf(float f) {
    union { float f; unsigned u; } v;
    v.f = f;
    unsigned r = v.u + 0x7FFFu + ((v.u >> 16) & 1u);
    return (u16)(r >> 16);
}

// ---------------------------------------------------------------- fused casts
__global__ __launch_bounds__(256) void cast_all(
    const float4* __restrict__ x,  const float4* __restrict__ wq,
    const float4* __restrict__ wk, const float4* __restrict__ wv,
    const float4* __restrict__ wo,
    ushort4* __restrict__ xo, ushort4* __restrict__ qo,
    ushort4* __restrict__ ko, ushort4* __restrict__ vo,
    ushort4* __restrict__ oo) {
    int bid = blockIdx.x;
    const float4* src; ushort4* dst; int i;
    if (bid < 4096) {
        src = x; dst = xo; i = bid * 256 + threadIdx.x;
    } else {
        int s = (bid - 4096) >> 10;
        int r = (bid - 4096) & 1023;
        src = (s == 0) ? wq : (s == 1) ? wk : (s == 2) ? wv : wo;
        dst = (s == 0) ? qo : (s == 1) ? ko : (s == 2) ? vo : oo;
        i = r * 256 + threadIdx.x;
    }
    float4 v = src[i];
    ushort4 o;
    o.x = f2bf(v.x); o.y = f2bf(v.y); o.z = f2bf(v.z); o.w = f2bf(v.w);
    dst[i] = o;
}

// ---------------------------------------------------------------- 128x128 GEMM core
// BK=64 phases (R21-proven): 2-deep 128x64 buffers (64 KB), counted vmcnt(8) +
// raw s_barrier, 32 MFMA per barrier-pair.
__device__ __forceinline__ void stage_tile64(const u16* __restrict__ g, int row0,
                                             int k0, u16* lds) {
    int t = threadIdx.x;
#pragma unroll
    for (int q = 0; q < 4; ++q) {
        int idx = q * 256 + t;          // 16B chunk 0..1023
        int row = idx >> 3;             // 0..127
        int col = idx & 7;
        int scol = col ^ (row & 7);     // pre-swizzled source chunk
        const u16* src = g + (long)(row0 + row) * CC + k0 + scol * 8;
        __builtin_amdgcn_global_load_lds(
            (const __attribute__((address_space(1))) void*)src,
            (__attribute__((address_space(3))) void*)(lds + idx * 8), 16, 0, 0);
    }
}

__device__ __forceinline__ void gemm_core(const u16* __restrict__ A,
                                          const u16* __restrict__ Bt,
                                          int blkM, int blkN,
                                          u16* sm,                // 32768 u16 (64 KB)
                                          f32x4 (&acc)[4][4]) {
    int lane = threadIdx.x & 63;
    int w = threadIdx.x >> 6;
    int wr = w >> 1, wc = w & 1;
    int l15 = lane & 15;
    int hi = lane >> 4;
    const int NT = CC / 64;             // 16 phases

    u16* bufA = sm;                     // 2 x 8192 u16
    u16* bufB = sm + 16384;             // 2 x 8192 u16

#pragma unroll
    for (int m = 0; m < 4; ++m)
#pragma unroll
        for (int n = 0; n < 4; ++n) acc[m][n] = (f32x4){0.f, 0.f, 0.f, 0.f};

    stage_tile64(A, blkM * 128, 0, bufA);
    stage_tile64(Bt, blkN * 128, 0, bufB);
    stage_tile64(A, blkM * 128, 64, bufA + 8192);
    stage_tile64(Bt, blkN * 128, 64, bufB + 8192);

    for (int kt = 0; kt < NT; ++kt) {
        if (kt + 1 < NT) {
            asm volatile("s_waitcnt vmcnt(8)" ::: "memory");
        } else {
            asm volatile("s_waitcnt vmcnt(0)" ::: "memory");
        }
        __builtin_amdgcn_s_barrier();
        __builtin_amdgcn_sched_barrier(0);

        u16* cA = bufA + (kt & 1) * 8192;
        u16* cB = bufB + (kt & 1) * 8192;

#pragma unroll
        for (int half = 0; half < 2; ++half) {
            bf16x8 af[4], bfr[4];
#pragma unroll
            for (int m = 0; m < 4; ++m) {
                int row = wr * 64 + m * 16 + l15;
                int ch = (half * 4 + hi) ^ (row & 7);
                af[m] = *(const bf16x8*)(cA + row * 64 + ch * 8);
            }
#pragma unroll
            for (int n = 0; n < 4; ++n) {
                int row = wc * 64 + n * 16 + l15;
                int ch = (half * 4 + hi) ^ (row & 7);
                bfr[n] = *(const bf16x8*)(cB + row * 64 + ch * 8);
            }
#pragma unroll
            for (int m = 0; m < 4; ++m)
#pragma unroll
                for (int n = 0; n < 4; ++n)
                    acc[m][n] = MFMA16(af[m], bfr[n], acc[m][n]);
        }

        __builtin_amdgcn_s_barrier();
        if (kt + 2 < NT) {
            stage_tile64(A, blkM * 128, (kt + 2) * 64, bufA + (kt & 1) * 8192);
            stage_tile64(Bt, blkN * 128, (kt + 2) * 64, bufB + (kt & 1) * 8192);
        }
    }
}

// Fused QKV projection. Q: row-major scaled. K, V: FRAGMENT-PACKED global layouts
// (4 KB tile per (b,h,kvblk32)); epilogue routes K/V through a packed-order LDS
// staging tile so global stores are coalesced 16B.
__global__ __launch_bounds__(256) void qkv_gemm(const u16* __restrict__ xb,
                                                const u16* __restrict__ wqb,
                                                const u16* __restrict__ wkb,
                                                const u16* __restrict__ wvb,
                                                u16* __restrict__ qo,
                                                u16* __restrict__ kpk,
                                                u16* __restrict__ vpk) {
    __shared__ u16 smem[8 * 128 * 32];  // 64 KB
    int seg = blockIdx.x >> 8;
    int bid = blockIdx.x & 255;
    int blkM = bid & 31, blkN = bid >> 5;
    const u16* Bt = (seg == 0) ? wqb : (seg == 1) ? wkb : wvb;
    f32x4 acc[4][4];
    gemm_core(xb, Bt, blkM, blkN, smem, acc);

    int lane = threadIdx.x & 63;
    int w = threadIdx.x >> 6, wr = w >> 1, wc = w & 1;
    int l15 = lane & 15, hi = lane >> 4;
    int r0 = blkM * 128 + wr * 64 + hi * 4;
    int c0 = blkN * 128 + wc * 64 + l15;

    if (seg == 0) {
        const float sc = 0.18033688011112042f;   // 1/8 * log2(e)
#pragma unroll
        for (int m = 0; m < 4; ++m)
#pragma unroll
            for (int n = 0; n < 4; ++n)
#pragma unroll
                for (int i = 0; i < 4; ++i)
                    qo[(long)(r0 + m * 16 + i) * CC + c0 + n * 16] =
                        f2bf(acc[m][n][i] * sc);
        return;
    }

    u16* sl = smem;                     // 16384 u16 = 8 subtiles x 2048
    __syncthreads();

    int ltb = wr * 64 + hi * 4;
    int lfb = wc * 64;
    if (seg == 1) {
#pragma unroll
        for (int m = 0; m < 4; ++m) {
            int lt = ltb + m * 16;
            int kvbl = lt >> 5;
#pragma unroll
            for (int n = 0; n < 4; ++n) {
                int lf = lfb + n * 16 + l15;
                int dd = lf & 63, hhl = lf >> 6;
                int base = ((kvbl << 1) + hhl) * 2048 + ((dd >> 3) << 8) + (dd & 7);
#pragma unroll
                for (int i = 0; i < 4; ++i)
                    sl[base + ((lt + i) & 31) * 8] = f2bf(acc[m][n][i]);
            }
        }
    } else {
#pragma unroll
        for (int m = 0; m < 4; ++m) {
            int lt = ltb + m * 16;
            int kvbl = lt >> 5, kv0 = lt & 31;
#pragma unroll
            for (int n = 0; n < 4; ++n) {
                int lf = lfb + n * 16 + l15;
                int dd = lf & 63, hhl = lf >> 6;
                int off = ((kvbl << 1) + hhl) * 2048 +
                          ((((dd >> 5) << 2) + (kv0 >> 3)) << 8) +
                          ((dd & 31) << 3) + (kv0 & 7);
                ushort4 p;
                p.x = f2bf(acc[m][n][0]); p.y = f2bf(acc[m][n][1]);
                p.z = f2bf(acc[m][n][2]); p.w = f2bf(acc[m][n][3]);
                *(ushort4*)(sl + off) = p;
            }
        }
    }
    __syncthreads();

    u16* pk = (seg == 1) ? kpk : vpk;
    int t = threadIdx.x;
    int b2 = blkM >> 4;
    int kvb_base = (blkM * 4) & 63;
#pragma unroll
    for (int q = 0; q < 8; ++q) {
        int kvbl = q >> 1, hhl = q & 1;
        long g = (((long)(b2 * 16 + blkN * 2 + hhl) * 64) + kvb_base + kvbl) << 11;
        bf16x8 v = *(const bf16x8*)(sl + q * 2048 + t * 8);
        *(bf16x8*)(pk + g + t * 8) = v;
    }
}

__global__ __launch_bounds__(256) void out_gemm(const u16* __restrict__ at,
                                                const u16* __restrict__ wob,
                                                const float* __restrict__ bias,
                                                float* __restrict__ out) {
    __shared__ u16 smem[8 * 128 * 32];
    int bid = blockIdx.x;
    int blkM = bid & 31, blkN = bid >> 5;
    f32x4 acc[4][4];
    gemm_core(at, wob, blkM, blkN, smem, acc);

    int lane = threadIdx.x & 63;
    int w = threadIdx.x >> 6, wr = w >> 1, wc = w & 1;
    int l15 = lane & 15, hi = lane >> 4;
    int r0 = blkM * 128 + wr * 64 + hi * 4;
    int c0 = blkN * 128 + wc * 64 + l15;
#pragma unroll
    for (int n = 0; n < 4; ++n) {
        int c = c0 + n * 16;
        float bv = bias[c];
#pragma unroll
        for (int m = 0; m < 4; ++m)
#pragma unroll
            for (int i = 0; i < 4; ++i)
                out[(long)(r0 + m * 16 + i) * CC + c] = acc[m][n][i] + bv;
    }
}

// ---------------------------------------------------------------- flash attention v20
// = R20 v18 (fragment-packed K/V, no loop barriers, fixed-exp softmax, 32 q-rows)
// + REGISTER PREFETCH: next subtile's 8 K/V fragments are loaded at the top of
// the iteration (issued a full iteration ahead of use) into a named second set.
__global__ __launch_bounds__(128, 4) void attn_fwd(const u16* __restrict__ Q,
                                                   const u16* __restrict__ Kp,
                                                   const u16* __restrict__ Vp,
                                                   u16* __restrict__ O) {
    __shared__ float xch[64 * 36];      // 9.2 KB merge scratch
    int lane = threadIdx.x & 63;
    int w = threadIdx.x >> 6;           // 0..1 = kv-parity
    int bh = blockIdx.x & 31;           // same bh -> same XCD (idx&7 = bh&7)
    int qt = 63 - (blockIdx.x >> 5);    // q-tile of 32 rows, heaviest first (LPT)
    int h = bh & 15, b = bh >> 4;
    int l31 = lane & 31, h5 = lane >> 5;

    int qg = qt * 32 + l31;             // this lane's q row
    int nt32 = qt + 1;                  // 32-kv subtiles total

    const u16* kbase = Kp + (((long)(b * 16 + h) * 64) << 11) + h5 * 256 + l31 * 8;
    const u16* vbase = Vp + (((long)(b * 16 + h) * 64) << 11) + h5 * 256 + l31 * 8;

    // Q fragments (B operand): col=l31 (q), k = m*16 + h5*8 + j  (loaded once)
    const u16* qrow = Q + (long)(b * TT + qg) * CC + h * SS + h5 * 8;
    bf16x8 qf[4];
#pragma unroll
    for (int m = 0; m < 4; ++m) qf[m] = *(const bf16x8*)(qrow + m * 16);

    f32x16 oa0 = {0.f}, oa1 = {0.f};    // O^T partial: d 0..31 / 32..63, col=q=l31
    f32x16 ls = {0.f};                  // vector partial row-sum of P

    // prologue: load subtile w's fragments
    bf16x8 kf0, kf1, kf2, kf3, v00, v01, v10, v11;
    {
        const u16* kt = kbase + ((long)w << 11);
        const u16* vt2 = vbase + ((long)w << 11);
        kf0 = *(const bf16x8*)(kt);
        kf1 = *(const bf16x8*)(kt + 512);
        kf2 = *(const bf16x8*)(kt + 1024);
        kf3 = *(const bf16x8*)(kt + 1536);
        v00 = *(const bf16x8*)(vt2);
        v01 = *(const bf16x8*)(vt2 + 512);
        v10 = *(const bf16x8*)(vt2 + 1024);
        v11 = *(const bf16x8*)(vt2 + 1536);
    }

#pragma unroll 1
    for (int tt = w; tt < nt32; tt += 2) {
        // prefetch next subtile (tt+2) fragments — issued before current compute
        bf16x8 nk0, nk1, nk2, nk3, nv00, nv01, nv10, nv11;
        if (tt + 2 < nt32) {
            const u16* kt = kbase + ((long)(tt + 2) << 11);
            const u16* vt2 = vbase + ((long)(tt + 2) << 11);
            nk0 = *(const bf16x8*)(kt);
            nk1 = *(const bf16x8*)(kt + 512);
            nk2 = *(const bf16x8*)(kt + 1024);
            nk3 = *(const bf16x8*)(kt + 1536);
            nv00 = *(const bf16x8*)(vt2);
            nv01 = *(const bf16x8*)(vt2 + 512);
            nv10 = *(const bf16x8*)(vt2 + 1024);
            nv11 = *(const bf16x8*)(vt2 + 1536);
        }

        // QK^T swapped: S^T = mfma(A=K, B=Q)
        f32x16 s0 = {0.f};
        __builtin_amdgcn_s_setprio(1);
        s0 = MFMA32(kf0, qf[0], s0);
        s0 = MFMA32(kf1, qf[1], s0);
        s0 = MFMA32(kf2, qf[2], s0);
        s0 = MFMA32(kf3, qf[3], s0);
        __builtin_amdgcn_s_setprio(0);

        if (tt == qt) {   // diagonal subtile: causal mask (kv > q)
            int kvb = tt * 32 + 4 * h5;
#pragma unroll
            for (int r = 0; r < 16; ++r) {
                int kv = kvb + (r & 3) + 8 * (r >> 2);
                if (kv > qg) s0[r] = -1e30f;
            }
        }

        // P = exp2(s - 16): fixed exponent (scores bounded |s| << 127)
        f32x16 p0v;
#pragma unroll
        for (int r = 0; r < 16; ++r) p0v[r] = __builtin_amdgcn_exp2f(s0[r] - 16.0f);
#pragma unroll
        for (int r = 0; r < 16; ++r) ls[r] += p0v[r];

        // In-register P -> B-fragment: cvt_pk + permlane32_swap(w0, w2)
        bf16x8 pf[2];
#pragma unroll
        for (int hk = 0; hk < 2; ++hk) {
            unsigned w0, w1, w2, w3;
            CVTPK(w0, p0v[8 * hk + 0], p0v[8 * hk + 1]);
            CVTPK(w1, p0v[8 * hk + 2], p0v[8 * hk + 3]);
            CVTPK(w2, p0v[8 * hk + 4], p0v[8 * hk + 5]);
            CVTPK(w3, p0v[8 * hk + 6], p0v[8 * hk + 7]);
            asm("v_permlane32_swap_b32 %0, %1" : "+v"(w0), "+v"(w2));
            asm("v_permlane32_swap_b32 %0, %1" : "+v"(w1), "+v"(w3));
            union { unsigned u[4]; bf16x8 v; } fb;
            fb.u[0] = w0; fb.u[1] = w1; fb.u[2] = w2; fb.u[3] = w3;
            pf[hk] = fb.v;
        }

        // PV: O^T[d][q] += V[d][kv] * P^T[kv][q]
        __builtin_amdgcn_s_setprio(1);
        oa0 = MFMA32(v00, pf[0], oa0);
        oa0 = MFMA32(v01, pf[1], oa0);
        oa1 = MFMA32(v10, pf[0], oa1);
        oa1 = MFMA32(v11, pf[1], oa1);
        __builtin_amdgcn_s_setprio(0);

        // rotate prefetched fragments into current (SSA renames, no copies)
        kf0 = nk0; kf1 = nk1; kf2 = nk2; kf3 = nk3;
        v00 = nv00; v01 = nv01; v10 = nv10; v11 = nv11;
    }

    // reduce l once: in-lane tree + partner exchange
    float l;
    {
        float t8[8];
#pragma unroll
        for (int r = 0; r < 8; ++r) t8[r] = ls[r] + ls[r + 8];
#pragma unroll
        for (int r = 0; r < 4; ++r) t8[r] = t8[r] + t8[r + 4];
        l = (t8[0] + t8[1]) + (t8[2] + t8[3]);
        l += __shfl_xor(l, 32);
    }

    // ---- merge the two kv-parity partials: (oaA + oaB) / (lA + lB) ----
    if (w == 1) {
        float* xl = xch + lane * 36;
#pragma unroll
        for (int r = 0; r < 16; ++r) { xl[r] = oa0[r]; xl[16 + r] = oa1[r]; }
        xl[32] = l;
    }
    __syncthreads();
    if (w == 0) {
        float* xl = xch + lane * 36;
        float inv = 1.0f / (l + xl[32]);

        u16* ob = O + (long)(b * TT + qg) * CC + h * SS;
#pragma unroll
        for (int rq = 0; rq < 4; ++rq) {
            float v00m = (oa0[rq * 4 + 0] + xl[rq * 4 + 0]) * inv;
            float v01m = (oa0[rq * 4 + 1] + xl[rq * 4 + 1]) * inv;
            float v02m = (oa0[rq * 4 + 2] + xl[rq * 4 + 2]) * inv;
            float v03m = (oa0[rq * 4 + 3] + xl[rq * 4 + 3]) * inv;
            float v10m = (oa1[rq * 4 + 0] + xl[16 + rq * 4 + 0]) * inv;
            float v11m = (oa1[rq * 4 + 1] + xl[16 + rq * 4 + 1]) * inv;
            float v12m = (oa1[rq * 4 + 2] + xl[16 + rq * 4 + 2]) * inv;
            float v13m = (oa1[rq * 4 + 3] + xl[16 + rq * 4 + 3]) * inv;
            unsigned a0, a1, c0, c1;
            CVTPK(a0, v00m, v01m);
            CVTPK(a1, v02m, v03m);
            CVTPK(c0, v10m, v11m);
            CVTPK(c1, v12m, v13m);
            uint2 ua, uc;
            ua.x = a0; ua.y = a1; uc.x = c0; uc.y = c1;
            *(uint2*)(ob + rq * 8 + h5 * 4) = ua;
            *(uint2*)(ob + 32 + rq * 8 + h5 * 4) = uc;
        }
    }
}

// ---------------------------------------------------------------- launch
extern "C" void kernel_launch(void* const* d_in, const int* in_sizes, int n_in,
                              void* d_out, int out_size, void* d_ws, size_t ws_size,
                              hipStream_t stream) {
    const float* x  = (const float*)d_in[0];
    const float* Wq = (const float*)d_in[1];
    const float* Wk = (const float*)d_in[2];
    const float* Wv = (const float*)d_in[3];
    const float* Wo = (const float*)d_in[4];
    const float* bo = (const float*)d_in[5];

    char* ws = (char*)d_ws;
    const size_t MB = 1024 * 1024;
    u16* x_bf  = (u16*)(ws);
    u16* wq_bf = (u16*)(ws + 8 * MB);
    u16* wk_bf = (u16*)(ws + 10 * MB);
    u16* wv_bf = (u16*)(ws + 12 * MB);
    u16* wo_bf = (u16*)(ws + 14 * MB);
    u16* q_bf  = (u16*)(ws + 16 * MB);
    u16* kpack = (u16*)(ws + 24 * MB);   // 8 MB fragment-packed K
    u16* vpack = (u16*)(ws + 32 * MB);   // 8 MB fragment-packed V
    u16* at_bf = (u16*)(ws + 40 * MB);

    cast_all<<<dim3(8192), dim3(256), 0, stream>>>(
        (const float4*)x, (const float4*)Wq, (const float4*)Wk,
        (const float4*)Wv, (const float4*)Wo,
        (ushort4*)x_bf, (ushort4*)wq_bf, (ushort4*)wk_bf,
        (ushort4*)wv_bf, (ushort4*)wo_bf);

    qkv_gemm<<<dim3(768), dim3(256), 0, stream>>>(x_bf, wq_bf, wk_bf, wv_bf,
                                                  q_bf, kpack, vpack);

    attn_fwd<<<dim3(2048), dim3(128), 0, stream>>>(q_bf, kpack, vpack, at_bf);

    out_gemm<<<dim3(256), dim3(256), 0, stream>>>(at_bf, wo_bf, bo, (float*)d_out);
}

// Round 24
// 82.430 us; speedup vs baseline: 1.7473x; 1.7473x over previous
//
#include <hip/hip_runtime.h>

// Problem constants: B=2, T=2048, C=1024, H=16, S=64
#define BB 2
#define TT 2048
#define CC 1024
#define HH 16
#define SS 64
#define MM (BB * TT)   // 4096

typedef unsigned short u16;
typedef __bf16 bf16x8 __attribute__((ext_vector_type(8)));
typedef float f32x4 __attribute__((ext_vector_type(4)));
typedef float f32x16 __attribute__((ext_vector_type(16)));

#define MFMA16(a, b, c) __builtin_amdgcn_mfma_f32_16x16x32_bf16((a), (b), (c), 0, 0, 0)
#define MFMA32(a, b, c) __builtin_amdgcn_mfma_f32_32x32x16_bf16((a), (b), (c), 0, 0, 0)
// v_cvt_pk_bf16_f32: D[15:0]=bf16(S0), D[31:16]=bf16(S1)
#define CVTPK(d, a, b) asm("v_cvt_pk_bf16_f32 %0, %1, %2" : "=v"(d) : "v"(a), "v"(b))

__device__ inline u16 f2bf(float f) {
    union { float f; unsigned u; } v;
    v.f = f;
    unsigned r = v.u + 0x7FFFu + ((v.u >> 16) & 1u);
    return (u16)(r >> 16);
}

// ---------------------------------------------------------------- fused casts
__global__ __launch_bounds__(256) void cast_all(
    const float4* __restrict__ x,  const float4* __restrict__ wq,
    const float4* __restrict__ wk, const float4* __restrict__ wv,
    const float4* __restrict__ wo,
    ushort4* __restrict__ xo, ushort4* __restrict__ qo,
    ushort4* __restrict__ ko, ushort4* __restrict__ vo,
    ushort4* __restrict__ oo) {
    int bid = blockIdx.x;
    const float4* src; ushort4* dst; int i;
    if (bid < 4096) {
        src = x; dst = xo; i = bid * 256 + threadIdx.x;
    } else {
        int s = (bid - 4096) >> 10;
        int r = (bid - 4096) & 1023;
        src = (s == 0) ? wq : (s == 1) ? wk : (s == 2) ? wv : wo;
        dst = (s == 0) ? qo : (s == 1) ? ko : (s == 2) ? vo : oo;
        i = r * 256 + threadIdx.x;
    }
    float4 v = src[i];
    ushort4 o;
    o.x = f2bf(v.x); o.y = f2bf(v.y); o.z = f2bf(v.z); o.w = f2bf(v.w);
    dst[i] = o;
}

// ---------------------------------------------------------------- 128x128 GEMM core
// BK=64 phases (R21-proven): 2-deep 128x64 buffers (64 KB), counted vmcnt(8) +
// raw s_barrier, 32 MFMA per barrier-pair.
__device__ __forceinline__ void stage_tile64(const u16* __restrict__ g, int row0,
                                             int k0, u16* lds) {
    int t = threadIdx.x;
#pragma unroll
    for (int q = 0; q < 4; ++q) {
        int idx = q * 256 + t;          // 16B chunk 0..1023
        int row = idx >> 3;             // 0..127
        int col = idx & 7;
        int scol = col ^ (row & 7);     // pre-swizzled source chunk
        const u16* src = g + (long)(row0 + row) * CC + k0 + scol * 8;
        __builtin_amdgcn_global_load_lds(
            (const __attribute__((address_space(1))) void*)src,
            (__attribute__((address_space(3))) void*)(lds + idx * 8), 16, 0, 0);
    }
}

__device__ __forceinline__ void gemm_core(const u16* __restrict__ A,
                                          const u16* __restrict__ Bt,
                                          int blkM, int blkN,
                                          u16* sm,                // 32768 u16 (64 KB)
                                          f32x4 (&acc)[4][4]) {
    int lane = threadIdx.x & 63;
    int w = threadIdx.x >> 6;
    int wr = w >> 1, wc = w & 1;
    int l15 = lane & 15;
    int hi = lane >> 4;
    const int NT = CC / 64;             // 16 phases

    u16* bufA = sm;                     // 2 x 8192 u16
    u16* bufB = sm + 16384;             // 2 x 8192 u16

#pragma unroll
    for (int m = 0; m < 4; ++m)
#pragma unroll
        for (int n = 0; n < 4; ++n) acc[m][n] = (f32x4){0.f, 0.f, 0.f, 0.f};

    stage_tile64(A, blkM * 128, 0, bufA);
    stage_tile64(Bt, blkN * 128, 0, bufB);
    stage_tile64(A, blkM * 128, 64, bufA + 8192);
    stage_tile64(Bt, blkN * 128, 64, bufB + 8192);

    for (int kt = 0; kt < NT; ++kt) {
        if (kt + 1 < NT) {
            asm volatile("s_waitcnt vmcnt(8)" ::: "memory");
        } else {
            asm volatile("s_waitcnt vmcnt(0)" ::: "memory");
        }
        __builtin_amdgcn_s_barrier();
        __builtin_amdgcn_sched_barrier(0);

        u16* cA = bufA + (kt & 1) * 8192;
        u16* cB = bufB + (kt & 1) * 8192;

#pragma unroll
        for (int half = 0; half < 2; ++half) {
            bf16x8 af[4], bfr[4];
#pragma unroll
            for (int m = 0; m < 4; ++m) {
                int row = wr * 64 + m * 16 + l15;
                int ch = (half * 4 + hi) ^ (row & 7);
                af[m] = *(const bf16x8*)(cA + row * 64 + ch * 8);
            }
#pragma unroll
            for (int n = 0; n < 4; ++n) {
                int row = wc * 64 + n * 16 + l15;
                int ch = (half * 4 + hi) ^ (row & 7);
                bfr[n] = *(const bf16x8*)(cB + row * 64 + ch * 8);
            }
#pragma unroll
            for (int m = 0; m < 4; ++m)
#pragma unroll
                for (int n = 0; n < 4; ++n)
                    acc[m][n] = MFMA16(af[m], bfr[n], acc[m][n]);
        }

        __builtin_amdgcn_s_barrier();
        if (kt + 2 < NT) {
            stage_tile64(A, blkM * 128, (kt + 2) * 64, bufA + (kt & 1) * 8192);
            stage_tile64(Bt, blkN * 128, (kt + 2) * 64, bufB + (kt & 1) * 8192);
        }
    }
}

// Fused QKV projection. Q: row-major scaled. K, V: FRAGMENT-PACKED global layouts
// (4 KB tile per (b,h,kvblk32)); epilogue routes K/V through a packed-order LDS
// staging tile so global stores are coalesced 16B.
//   K inner: (d>>3)*256 + kv*8 + (d&7)
//   V inner: ((d>>5)*4 + (kv>>3))*256 + (d&31)*8 + (kv&7)
__global__ __launch_bounds__(256) void qkv_gemm(const u16* __restrict__ xb,
                                                const u16* __restrict__ wqb,
                                                const u16* __restrict__ wkb,
                                                const u16* __restrict__ wvb,
                                                u16* __restrict__ qo,
                                                u16* __restrict__ kpk,
                                                u16* __restrict__ vpk) {
    __shared__ u16 smem[8 * 128 * 32];  // 64 KB
    int seg = blockIdx.x >> 8;
    int bid = blockIdx.x & 255;
    int blkM = bid & 31, blkN = bid >> 5;
    const u16* Bt = (seg == 0) ? wqb : (seg == 1) ? wkb : wvb;
    f32x4 acc[4][4];
    gemm_core(xb, Bt, blkM, blkN, smem, acc);

    int lane = threadIdx.x & 63;
    int w = threadIdx.x >> 6, wr = w >> 1, wc = w & 1;
    int l15 = lane & 15, hi = lane >> 4;
    int r0 = blkM * 128 + wr * 64 + hi * 4;
    int c0 = blkN * 128 + wc * 64 + l15;

    if (seg == 0) {
        const float sc = 0.18033688011112042f;   // 1/8 * log2(e)
#pragma unroll
        for (int m = 0; m < 4; ++m)
#pragma unroll
            for (int n = 0; n < 4; ++n)
#pragma unroll
                for (int i = 0; i < 4; ++i)
                    qo[(long)(r0 + m * 16 + i) * CC + c0 + n * 16] =
                        f2bf(acc[m][n][i] * sc);
        return;
    }

    u16* sl = smem;                     // 16384 u16 = 8 subtiles x 2048
    __syncthreads();

    int ltb = wr * 64 + hi * 4;
    int lfb = wc * 64;
    if (seg == 1) {
#pragma unroll
        for (int m = 0; m < 4; ++m) {
            int lt = ltb + m * 16;
            int kvbl = lt >> 5;
#pragma unroll
            for (int n = 0; n < 4; ++n) {
                int lf = lfb + n * 16 + l15;
                int dd = lf & 63, hhl = lf >> 6;
                int base = ((kvbl << 1) + hhl) * 2048 + ((dd >> 3) << 8) + (dd & 7);
#pragma unroll
                for (int i = 0; i < 4; ++i)
                    sl[base + ((lt + i) & 31) * 8] = f2bf(acc[m][n][i]);
            }
        }
    } else {
#pragma unroll
        for (int m = 0; m < 4; ++m) {
            int lt = ltb + m * 16;
            int kvbl = lt >> 5, kv0 = lt & 31;
#pragma unroll
            for (int n = 0; n < 4; ++n) {
                int lf = lfb + n * 16 + l15;
                int dd = lf & 63, hhl = lf >> 6;
                int off = ((kvbl << 1) + hhl) * 2048 +
                          ((((dd >> 5) << 2) + (kv0 >> 3)) << 8) +
                          ((dd & 31) << 3) + (kv0 & 7);
                ushort4 p;
                p.x = f2bf(acc[m][n][0]); p.y = f2bf(acc[m][n][1]);
                p.z = f2bf(acc[m][n][2]); p.w = f2bf(acc[m][n][3]);
                *(ushort4*)(sl + off) = p;
            }
        }
    }
    __syncthreads();

    u16* pk = (seg == 1) ? kpk : vpk;
    int t = threadIdx.x;
    int b2 = blkM >> 4;
    int kvb_base = (blkM * 4) & 63;
#pragma unroll
    for (int q = 0; q < 8; ++q) {
        int kvbl = q >> 1, hhl = q & 1;
        long g = (((long)(b2 * 16 + blkN * 2 + hhl) * 64) + kvb_base + kvbl) << 11;
        bf16x8 v = *(const bf16x8*)(sl + q * 2048 + t * 8);
        *(bf16x8*)(pk + g + t * 8) = v;
    }
}

__global__ __launch_bounds__(256) void out_gemm(const u16* __restrict__ at,
                                                const u16* __restrict__ wob,
                                                const float* __restrict__ bias,
                                                float* __restrict__ out) {
    __shared__ u16 smem[8 * 128 * 32];
    int bid = blockIdx.x;
    int blkM = bid & 31, blkN = bid >> 5;
    f32x4 acc[4][4];
    gemm_core(at, wob, blkM, blkN, smem, acc);

    int lane = threadIdx.x & 63;
    int w = threadIdx.x >> 6, wr = w >> 1, wc = w & 1;
    int l15 = lane & 15, hi = lane >> 4;
    int r0 = blkM * 128 + wr * 64 + hi * 4;
    int c0 = blkN * 128 + wc * 64 + l15;
#pragma unroll
    for (int n = 0; n < 4; ++n) {
        int c = c0 + n * 16;
        float bv = bias[c];
#pragma unroll
        for (int m = 0; m < 4; ++m)
#pragma unroll
            for (int i = 0; i < 4; ++i)
                out[(long)(r0 + m * 16 + i) * CC + c] = acc[m][n][i] + bv;
    }
}

// ---------------------------------------------------------------- flash attention v18 (R20/R21-proven, 82.3 us config)
// Fragment-packed global K/V, no loop barriers, fixed-exponent softmax
// P = exp2(s - 16); l accumulated vectorially, reduced once after the loop.
__global__ __launch_bounds__(128, 4) void attn_fwd(const u16* __restrict__ Q,
                                                   const u16* __restrict__ Kp,
                                                   const u16* __restrict__ Vp,
                                                   u16* __restrict__ O) {
    __shared__ float xch[64 * 36];      // 9.2 KB merge scratch
    int lane = threadIdx.x & 63;
    int w = threadIdx.x >> 6;           // 0..1 = kv-parity
    int bh = blockIdx.x & 31;           // same bh -> same XCD (idx&7 = bh&7)
    int qt = 63 - (blockIdx.x >> 5);    // q-tile of 32 rows, heaviest first (LPT)
    int h = bh & 15, b = bh >> 4;
    int l31 = lane & 31, h5 = lane >> 5;

    int qg = qt * 32 + l31;             // this lane's q row
    int nt32 = qt + 1;                  // 32-kv subtiles total

    const u16* kbase = Kp + (((long)(b * 16 + h) * 64) << 11) + h5 * 256 + l31 * 8;
    const u16* vbase = Vp + (((long)(b * 16 + h) * 64) << 11) + h5 * 256 + l31 * 8;

    // Q fragments (B operand): col=l31 (q), k = m*16 + h5*8 + j  (loaded once)
    const u16* qrow = Q + (long)(b * TT + qg) * CC + h * SS + h5 * 8;
    bf16x8 qf[4];
#pragma unroll
    for (int m = 0; m < 4; ++m) qf[m] = *(const bf16x8*)(qrow + m * 16);

    f32x16 oa0 = {0.f}, oa1 = {0.f};    // O^T partial: d 0..31 / 32..63, col=q=l31
    f32x16 ls = {0.f};                  // vector partial row-sum of P

#pragma unroll 1
    for (int tt = w; tt < nt32; tt += 2) {
        const u16* kt = kbase + ((long)tt << 11);
        const u16* vt2 = vbase + ((long)tt << 11);

        // K fragments: block (2m + h5), lane l31 -> coalesced 16B loads
        bf16x8 kf0 = *(const bf16x8*)(kt);
        bf16x8 kf1 = *(const bf16x8*)(kt + 512);
        bf16x8 kf2 = *(const bf16x8*)(kt + 1024);
        bf16x8 kf3 = *(const bf16x8*)(kt + 1536);
        // V fragments: block (4*d_half + 2*hk + h5)
        bf16x8 v00 = *(const bf16x8*)(vt2);
        bf16x8 v01 = *(const bf16x8*)(vt2 + 512);
        bf16x8 v10 = *(const bf16x8*)(vt2 + 1024);
        bf16x8 v11 = *(const bf16x8*)(vt2 + 1536);

        // QK^T swapped: S^T = mfma(A=K, B=Q)
        f32x16 s0 = {0.f};
        __builtin_amdgcn_s_setprio(1);
        s0 = MFMA32(kf0, qf[0], s0);
        s0 = MFMA32(kf1, qf[1], s0);
        s0 = MFMA32(kf2, qf[2], s0);
        s0 = MFMA32(kf3, qf[3], s0);
        __builtin_amdgcn_s_setprio(0);

        if (tt == qt) {   // diagonal subtile: causal mask (kv > q)
            int kvb = tt * 32 + 4 * h5;
#pragma unroll
            for (int r = 0; r < 16; ++r) {
                int kv = kvb + (r & 3) + 8 * (r >> 2);
                if (kv > qg) s0[r] = -1e30f;
            }
        }

        // P = exp2(s - 16): fixed exponent (scores bounded |s| << 127)
        f32x16 p0v;
#pragma unroll
        for (int r = 0; r < 16; ++r) p0v[r] = __builtin_amdgcn_exp2f(s0[r] - 16.0f);
#pragma unroll
        for (int r = 0; r < 16; ++r) ls[r] += p0v[r];

        // In-register P -> B-fragment: cvt_pk + permlane32_swap(w0, w2)
        bf16x8 pf[2];
#pragma unroll
        for (int hk = 0; hk < 2; ++hk) {
            unsigned w0, w1, w2, w3;
            CVTPK(w0, p0v[8 * hk + 0], p0v[8 * hk + 1]);
            CVTPK(w1, p0v[8 * hk + 2], p0v[8 * hk + 3]);
            CVTPK(w2, p0v[8 * hk + 4], p0v[8 * hk + 5]);
            CVTPK(w3, p0v[8 * hk + 6], p0v[8 * hk + 7]);
            asm("v_permlane32_swap_b32 %0, %1" : "+v"(w0), "+v"(w2));
            asm("v_permlane32_swap_b32 %0, %1" : "+v"(w1), "+v"(w3));
            union { unsigned u[4]; bf16x8 v; } fb;
            fb.u[0] = w0; fb.u[1] = w1; fb.u[2] = w2; fb.u[3] = w3;
            pf[hk] = fb.v;
        }

        // PV: O^T[d][q] += V[d][kv] * P^T[kv][q]
        __builtin_amdgcn_s_setprio(1);
        oa0 = MFMA32(v00, pf[0], oa0);
        oa0 = MFMA32(v01, pf[1], oa0);
        oa1 = MFMA32(v10, pf[0], oa1);
        oa1 = MFMA32(v11, pf[1], oa1);
        __builtin_amdgcn_s_setprio(0);
    }

    // reduce l once: in-lane tree + partner exchange
    float l;
    {
        float t8[8];
#pragma unroll
        for (int r = 0; r < 8; ++r) t8[r] = ls[r] + ls[r + 8];
#pragma unroll
        for (int r = 0; r < 4; ++r) t8[r] = t8[r] + t8[r + 4];
        l = (t8[0] + t8[1]) + (t8[2] + t8[3]);
        l += __shfl_xor(l, 32);
    }

    // ---- merge the two kv-parity partials: (oaA + oaB) / (lA + lB) ----
    if (w == 1) {
        float* xl = xch + lane * 36;
#pragma unroll
        for (int r = 0; r < 16; ++r) { xl[r] = oa0[r]; xl[16 + r] = oa1[r]; }
        xl[32] = l;
    }
    __syncthreads();
    if (w == 0) {
        float* xl = xch + lane * 36;
        float inv = 1.0f / (l + xl[32]);

        u16* ob = O + (long)(b * TT + qg) * CC + h * SS;
#pragma unroll
        for (int rq = 0; rq < 4; ++rq) {
            float v00 = (oa0[rq * 4 + 0] + xl[rq * 4 + 0]) * inv;
            float v01 = (oa0[rq * 4 + 1] + xl[rq * 4 + 1]) * inv;
            float v02 = (oa0[rq * 4 + 2] + xl[rq * 4 + 2]) * inv;
            float v03 = (oa0[rq * 4 + 3] + xl[rq * 4 + 3]) * inv;
            float v10 = (oa1[rq * 4 + 0] + xl[16 + rq * 4 + 0]) * inv;
            float v11 = (oa1[rq * 4 + 1] + xl[16 + rq * 4 + 1]) * inv;
            float v12 = (oa1[rq * 4 + 2] + xl[16 + rq * 4 + 2]) * inv;
            float v13 = (oa1[rq * 4 + 3] + xl[16 + rq * 4 + 3]) * inv;
            unsigned a0, a1, c0, c1;
            CVTPK(a0, v00, v01);
            CVTPK(a1, v02, v03);
            CVTPK(c0, v10, v11);
            CVTPK(c1, v12, v13);
            uint2 ua, uc;
            ua.x = a0; ua.y = a1; uc.x = c0; uc.y = c1;
            *(uint2*)(ob + rq * 8 + h5 * 4) = ua;
            *(uint2*)(ob + 32 + rq * 8 + h5 * 4) = uc;
        }
    }
}

// ---------------------------------------------------------------- launch
extern "C" void kernel_launch(void* const* d_in, const int* in_sizes, int n_in,
                              void* d_out, int out_size, void* d_ws, size_t ws_size,
                              hipStream_t stream) {
    const float* x  = (const float*)d_in[0];
    const float* Wq = (const float*)d_in[1];
    const float* Wk = (const float*)d_in[2];
    const float* Wv = (const float*)d_in[3];
    const float* Wo = (const float*)d_in[4];
    const float* bo = (const float*)d_in[5];

    char* ws = (char*)d_ws;
    const size_t MB = 1024 * 1024;
    u16* x_bf  = (u16*)(ws);
    u16* wq_bf = (u16*)(ws + 8 * MB);
    u16* wk_bf = (u16*)(ws + 10 * MB);
    u16* wv_bf = (u16*)(ws + 12 * MB);
    u16* wo_bf = (u16*)(ws + 14 * MB);
    u16* q_bf  = (u16*)(ws + 16 * MB);
    u16* kpack = (u16*)(ws + 24 * MB);   // 8 MB fragment-packed K
    u16* vpack = (u16*)(ws + 32 * MB);   // 8 MB fragment-packed V
    u16* at_bf = (u16*)(ws + 40 * MB);

    cast_all<<<dim3(8192), dim3(256), 0, stream>>>(
        (const float4*)x, (const float4*)Wq, (const float4*)Wk,
        (const float4*)Wv, (const float4*)Wo,
        (ushort4*)x_bf, (ushort4*)wq_bf, (ushort4*)wk_bf,
        (ushort4*)wv_bf, (ushort4*)wo_bf);

    qkv_gemm<<<dim3(768), dim3(256), 0, stream>>>(x_bf, wq_bf, wk_bf, wv_bf,
                                                  q_bf, kpack, vpack);

    attn_fwd<<<dim3(2048), dim3(128), 0, stream>>>(q_bf, kpack, vpack, at_bf);

    out_gemm<<<dim3(256), dim3(256), 0, stream>>>(at_bf, wo_bf, bo, (float*)d_out);
}